// Round 4
// baseline (229.072 us; speedup 1.0000x reference)
//
#include <hip/hip_runtime.h>

// AssistedExcitation: out = x * (1 + ALPHA * att(b,h,w))
// att = 5x5-gaussian-smoothed union mask of 32 boxes, per batch.
// x: [16,256,80,80] fp32, boxes: [16,32,4] fp32, kernel: [1,1,5,5] fp32.
//
// Two-kernel design (round 3 post-mortem: fused one-row-per-block kernel was
// latency-bound — Occupancy 11%, VALUBusy 6%, 2.27 TB/s):
//   K1: per-batch rasterize + 5x5 conv -> fac[B][H][W] in d_ws (1.6 MB, ~3us)
//   K2: pure grid streaming, 3200 blocks x 256 thr, 8 indep float4/thread,
//       factor hoisted (per-thread fac index invariant across the 8 iters).

namespace {
constexpr int kB = 16;
constexpr int kC = 256;
constexpr int kH = 80;
constexpr int kW = 80;
constexpr int kNBox = 32;
constexpr float kAlpha = 1.0f;
constexpr int kHW = kH * kW;            // 6400 floats per (b)
constexpr int kHW4 = kHW / 4;           // 1600 float4 per (b)
constexpr int kBF4 = kC * kHW4;         // 409600 float4 per batch image
constexpr size_t kWsNeed = (size_t)kB * kHW * sizeof(float);

__device__ __forceinline__ int reflect_idx(int r, int n) {
    // jnp.pad mode='reflect': -1 -> 1, -2 -> 2 ; n -> n-2, n+1 -> n-3
    return r < 0 ? -r : (r > n - 1 ? 2 * (n - 1) - r : r);
}
}  // namespace

// ---------------- K1: fac[b][h][w] = 1 + alpha * smooth(mask) ----------------
// grid = kB blocks, 256 threads
__global__ __launch_bounds__(256) void ae_rasterize_kernel(
    const float* __restrict__ boxes,
    const float* __restrict__ gk,
    float* __restrict__ fac)
{
    __shared__ int sx1[kNBox], sy1[kNBox], sx2[kNBox], sy2[kNBox];
    __shared__ float sk[25];
    __shared__ float smask[kH][kW];

    const int b = blockIdx.x;
    const int t = threadIdx.x;

    if (t < kNBox) {
        const float* bp = boxes + (size_t)(b * kNBox + t) * 4;
        float xc = bp[0], yc = bp[1], bw = bp[2], bh = bp[3];
        float fx1 = fmaxf(0.0f, truncf((xc - bw * 0.5f) * (float)kW));
        float fy1 = fmaxf(0.0f, truncf((yc - bh * 0.5f) * (float)kH));
        float fx2 = fminf((float)(kW - 1), truncf((xc + bw * 0.5f) * (float)kW));
        float fy2 = fminf((float)(kH - 1), truncf((yc + bh * 0.5f) * (float)kH));
        int ix1 = (int)fx1, iy1 = (int)fy1, ix2 = (int)fx2, iy2 = (int)fy2;
        bool valid = (ix2 > ix1) && (iy2 > iy1);
        sx1[t] = ix1;
        sx2[t] = ix2;
        sy1[t] = valid ? iy1 : 1;   // empty range when invalid
        sy2[t] = valid ? iy2 : 0;
    } else if (t >= 64 && t < 64 + 25) {
        sk[t - 64] = gk[t - 64];
    }
    __syncthreads();

    // union mask over 32 boxes
    for (int p = t; p < kHW; p += 256) {
        int h = p / kW, w = p % kW;
        float m = 0.0f;
#pragma unroll
        for (int n = 0; n < kNBox; ++n) {
            bool in = (h >= sy1[n]) && (h <= sy2[n]) && (w >= sx1[n]) && (w <= sx2[n]);
            m = in ? 1.0f : m;
        }
        smask[h][w] = m;
    }
    __syncthreads();

    // 5x5 gaussian with reflect padding -> factor
    for (int p = t; p < kHW; p += 256) {
        int h = p / kW, w = p % kW;
        float acc = 0.0f;
#pragma unroll
        for (int i = 0; i < 5; ++i) {
            int rr = reflect_idx(h + i - 2, kH);
#pragma unroll
            for (int j = 0; j < 5; ++j) {
                int cc = reflect_idx(w + j - 2, kW);
                acc += sk[i * 5 + j] * smask[rr][cc];
            }
        }
        fac[(size_t)b * kHW + p] = 1.0f + kAlpha * acc;
    }
}

// ---------------- K2: out = x * fac (pure streaming) ----------------
// grid = kB * 200 = 3200 blocks x 256 threads; 8 float4 per thread.
// Mapping: within batch b, element index = k*51200 + off, off in [0,51200),
// k in [0,8). 51200 % 1600 == 0 -> the (h,w4) index (= off % 1600) and thus
// the factor are invariant across k; channel c = k*32 + off/1600.
__global__ __launch_bounds__(256) void ae_stream_kernel(
    const float4* __restrict__ x4,
    const float4* __restrict__ fac4,
    float4* __restrict__ o4)
{
    const int blk = blockIdx.x;
    const int b = blk / 200;
    const int off = (blk % 200) * 256 + threadIdx.x;     // [0, 51200)
    const float4 f = fac4[b * kHW4 + (off % kHW4)];
    const size_t base = (size_t)b * kBF4 + off;
#pragma unroll
    for (int k = 0; k < 8; ++k) {
        size_t idx = base + (size_t)k * 51200;
        float4 v = x4[idx];
        v.x *= f.x;
        v.y *= f.y;
        v.z *= f.z;
        v.w *= f.w;
        o4[idx] = v;
    }
}

// ---------------- fallback: round-3 fused kernel (if ws too small) ----------
__global__ __launch_bounds__(320) void ae_fused_kernel(
    const float* __restrict__ x,
    const float* __restrict__ boxes,
    const float* __restrict__ gk,
    float* __restrict__ out)
{
    __shared__ int sx1[kNBox], sy1[kNBox], sx2[kNBox], sy2[kNBox];
    __shared__ float sk[25];
    __shared__ float smask[5][kW];
    __shared__ __attribute__((aligned(16))) float sfac[kW];

    const int b = blockIdx.x / kH;
    const int h = blockIdx.x % kH;
    const int t = threadIdx.x;

    if (t < kNBox) {
        const float* bp = boxes + (size_t)(b * kNBox + t) * 4;
        float xc = bp[0], yc = bp[1], bw = bp[2], bh = bp[3];
        float fx1 = fmaxf(0.0f, truncf((xc - bw * 0.5f) * (float)kW));
        float fy1 = fmaxf(0.0f, truncf((yc - bh * 0.5f) * (float)kH));
        float fx2 = fminf((float)(kW - 1), truncf((xc + bw * 0.5f) * (float)kW));
        float fy2 = fminf((float)(kH - 1), truncf((yc + bh * 0.5f) * (float)kH));
        int ix1 = (int)fx1, iy1 = (int)fy1, ix2 = (int)fx2, iy2 = (int)fy2;
        bool valid = (ix2 > ix1) && (iy2 > iy1);
        sx1[t] = ix1;
        sx2[t] = ix2;
        sy1[t] = valid ? iy1 : 1;
        sy2[t] = valid ? iy2 : 0;
    } else if (t >= 64 && t < 64 + 25) {
        sk[t - 64] = gk[t - 64];
    }
    __syncthreads();

    for (int p = t; p < 5 * kW; p += 320) {
        int i = p / kW, c = p % kW;
        int rr = reflect_idx(h + i - 2, kH);
        float m = 0.0f;
#pragma unroll
        for (int n = 0; n < kNBox; ++n) {
            bool in = (rr >= sy1[n]) && (rr <= sy2[n]) && (c >= sx1[n]) && (c <= sx2[n]);
            m = in ? 1.0f : m;
        }
        smask[i][c] = m;
    }
    __syncthreads();

    if (t < kW) {
        float acc = 0.0f;
#pragma unroll
        for (int i = 0; i < 5; ++i) {
#pragma unroll
            for (int j = 0; j < 5; ++j) {
                int cc = reflect_idx(t + j - 2, kW);
                acc += sk[i * 5 + j] * smask[i][cc];
            }
        }
        sfac[t] = 1.0f + kAlpha * acc;
    }
    __syncthreads();

    const int j = t % 20;
    const int c0 = t / 20;
    const float4 f4 = *reinterpret_cast<const float4*>(&sfac[j * 4]);
    const size_t rowbase = (size_t)b * (kC * kH * kW / 4) + (size_t)h * (kW / 4);
    const float4* x4 = reinterpret_cast<const float4*>(x) + rowbase;
    float4* o4 = reinterpret_cast<float4*>(out) + rowbase;
#pragma unroll
    for (int it = 0; it < kC / 16; ++it) {
        int c = c0 + it * 16;
        size_t off = (size_t)c * (kH * kW / 4) + j;
        float4 v = x4[off];
        v.x *= f4.x;
        v.y *= f4.y;
        v.z *= f4.z;
        v.w *= f4.w;
        o4[off] = v;
    }
}

extern "C" void kernel_launch(void* const* d_in, const int* in_sizes, int n_in,
                              void* d_out, int out_size, void* d_ws, size_t ws_size,
                              hipStream_t stream) {
    const float* x     = (const float*)d_in[0];
    const float* boxes = (const float*)d_in[1];
    const float* gk    = (const float*)d_in[2];
    float* out         = (float*)d_out;

    if (ws_size >= kWsNeed) {
        float* fac = (float*)d_ws;
        ae_rasterize_kernel<<<dim3(kB), dim3(256), 0, stream>>>(boxes, gk, fac);
        ae_stream_kernel<<<dim3(kB * 200), dim3(256), 0, stream>>>(
            (const float4*)x, (const float4*)fac, (float4*)out);
    } else {
        ae_fused_kernel<<<dim3(kB * kH), dim3(320), 0, stream>>>(x, boxes, gk, out);
    }
}

// Round 10
// 192.166 us; speedup vs baseline: 1.1921x; 1.1921x over previous
//
#include <hip/hip_runtime.h>

// AssistedExcitation: out = x * (1 + ALPHA * att(b,h,w))
// att = 5x5-gaussian-smoothed union mask of 32 boxes, per batch.
// x: [16,256,80,80] fp32, boxes: [16,32,4] fp32, kernel: [1,1,5,5] fp32.
//
// Round-4 post-mortem: stream kernel was latency-bound (VGPR=24 -> compiler
// serialized load/store pairs, 1 outstanding read/thread, 2.53 TB/s while the
// harness fill kernel hits 6.6 TB/s). Fix: register-batch 8 independent loads
// (static-index float4 v[8]) then multiply+nontemporal-store; K1 parallelized
// to 160 blocks (8-row stripes) so it costs ~1-2 us.
// Round-6: __builtin_nontemporal_store needs a clang ext_vector_type, not
// HIP_vector_type<float,4> -> bit-cast through vfloat4.

namespace {
constexpr int kB = 16;
constexpr int kC = 256;
constexpr int kH = 80;
constexpr int kW = 80;
constexpr int kNBox = 32;
constexpr float kAlpha = 1.0f;
constexpr int kHW = kH * kW;            // 6400 floats per (b)
constexpr int kHW4 = kHW / 4;           // 1600 float4 per (b)
constexpr int kBF4 = kC * kHW4;         // 409600 float4 per batch image
constexpr size_t kWsNeed = (size_t)kB * kHW * sizeof(float);

typedef float vfloat4 __attribute__((ext_vector_type(4)));

__device__ __forceinline__ int reflect_idx(int r, int n) {
    // jnp.pad mode='reflect': -1 -> 1, -2 -> 2 ; n -> n-2, n+1 -> n-3
    return r < 0 ? -r : (r > n - 1 ? 2 * (n - 1) - r : r);
}
}  // namespace

// ---------------- K1: fac[b][h][w] = 1 + alpha * smooth(mask) ----------------
// grid = kB * 10 blocks (one per batch x 8-row stripe), 256 threads
__global__ __launch_bounds__(256) void ae_rasterize_kernel(
    const float* __restrict__ boxes,
    const float* __restrict__ gk,
    float* __restrict__ fac)
{
    __shared__ int sx1[kNBox], sy1[kNBox], sx2[kNBox], sy2[kNBox];
    __shared__ float sk[25];
    __shared__ float smask[12][kW];   // rows h0-2 .. h0+9 (reflected)

    const int b = blockIdx.x / 10;
    const int h0 = (blockIdx.x % 10) * 8;
    const int t = threadIdx.x;

    if (t < kNBox) {
        const float* bp = boxes + (size_t)(b * kNBox + t) * 4;
        float xc = bp[0], yc = bp[1], bw = bp[2], bh = bp[3];
        float fx1 = fmaxf(0.0f, truncf((xc - bw * 0.5f) * (float)kW));
        float fy1 = fmaxf(0.0f, truncf((yc - bh * 0.5f) * (float)kH));
        float fx2 = fminf((float)(kW - 1), truncf((xc + bw * 0.5f) * (float)kW));
        float fy2 = fminf((float)(kH - 1), truncf((yc + bh * 0.5f) * (float)kH));
        int ix1 = (int)fx1, iy1 = (int)fy1, ix2 = (int)fx2, iy2 = (int)fy2;
        bool valid = (ix2 > ix1) && (iy2 > iy1);
        sx1[t] = ix1;
        sx2[t] = ix2;
        sy1[t] = valid ? iy1 : 1;   // empty range when invalid
        sy2[t] = valid ? iy2 : 0;
    } else if (t >= 64 && t < 64 + 25) {
        sk[t - 64] = gk[t - 64];
    }
    __syncthreads();

    // union mask over 32 boxes for the 12 (reflected) rows this stripe needs
    for (int p = t; p < 12 * kW; p += 256) {
        int lr = p / kW, w = p % kW;
        int h = reflect_idx(h0 - 2 + lr, kH);
        float m = 0.0f;
#pragma unroll
        for (int n = 0; n < kNBox; ++n) {
            bool in = (h >= sy1[n]) && (h <= sy2[n]) && (w >= sx1[n]) && (w <= sx2[n]);
            m = in ? 1.0f : m;
        }
        smask[lr][w] = m;
    }
    __syncthreads();

    // 5x5 gaussian with reflect padding -> factor, for rows h0 .. h0+7
    for (int p = t; p < 8 * kW; p += 256) {
        int r = p / kW, w = p % kW;   // local row, col
        float acc = 0.0f;
#pragma unroll
        for (int i = 0; i < 5; ++i) {
#pragma unroll
            for (int j = 0; j < 5; ++j) {
                int cc = reflect_idx(w + j - 2, kW);
                acc += sk[i * 5 + j] * smask[r + i][cc];
            }
        }
        fac[(size_t)b * kHW + (size_t)(h0 + r) * kW + w] = 1.0f + kAlpha * acc;
    }
}

// ---------------- K2: out = x * fac (pure streaming, MLP-forced) ------------
// grid = kB * 200 = 3200 blocks x 256 threads; 8 float4 per thread.
// Mapping: within batch b, element index = k*51200 + off, off in [0,51200),
// k in [0,8). 51200 % 1600 == 0 -> the (h,w4) index (= off % 1600) and thus
// the factor are invariant across k; channel c = k*32 + off/1600.
__global__ __launch_bounds__(256) void ae_stream_kernel(
    const vfloat4* __restrict__ x4,
    const vfloat4* __restrict__ fac4,
    vfloat4* __restrict__ o4)
{
    const int blk = blockIdx.x;
    const int b = blk / 200;
    const int off = (blk % 200) * 256 + threadIdx.x;     // [0, 51200)
    const vfloat4 f = fac4[b * kHW4 + (off % kHW4)];
    const size_t base = (size_t)b * kBF4 + off;

    // Phase A: issue all 8 independent loads (static indices -> registers).
    vfloat4 v[8];
#pragma unroll
    for (int k = 0; k < 8; ++k) {
        v[k] = x4[base + (size_t)k * 51200];
    }
    // Phase B: scale and store (nontemporal: out is write-once, keep x in L3).
#pragma unroll
    for (int k = 0; k < 8; ++k) {
        vfloat4 w = v[k] * f;
        __builtin_nontemporal_store(w, &o4[base + (size_t)k * 51200]);
    }
}

// ---------------- fallback: round-3 fused kernel (if ws too small) ----------
__global__ __launch_bounds__(320) void ae_fused_kernel(
    const float* __restrict__ x,
    const float* __restrict__ boxes,
    const float* __restrict__ gk,
    float* __restrict__ out)
{
    __shared__ int sx1[kNBox], sy1[kNBox], sx2[kNBox], sy2[kNBox];
    __shared__ float sk[25];
    __shared__ float smask[5][kW];
    __shared__ __attribute__((aligned(16))) float sfac[kW];

    const int b = blockIdx.x / kH;
    const int h = blockIdx.x % kH;
    const int t = threadIdx.x;

    if (t < kNBox) {
        const float* bp = boxes + (size_t)(b * kNBox + t) * 4;
        float xc = bp[0], yc = bp[1], bw = bp[2], bh = bp[3];
        float fx1 = fmaxf(0.0f, truncf((xc - bw * 0.5f) * (float)kW));
        float fy1 = fmaxf(0.0f, truncf((yc - bh * 0.5f) * (float)kH));
        float fx2 = fminf((float)(kW - 1), truncf((xc + bw * 0.5f) * (float)kW));
        float fy2 = fminf((float)(kH - 1), truncf((yc + bh * 0.5f) * (float)kH));
        int ix1 = (int)fx1, iy1 = (int)fy1, ix2 = (int)fx2, iy2 = (int)fy2;
        bool valid = (ix2 > ix1) && (iy2 > iy1);
        sx1[t] = ix1;
        sx2[t] = ix2;
        sy1[t] = valid ? iy1 : 1;
        sy2[t] = valid ? iy2 : 0;
    } else if (t >= 64 && t < 64 + 25) {
        sk[t - 64] = gk[t - 64];
    }
    __syncthreads();

    for (int p = t; p < 5 * kW; p += 320) {
        int i = p / kW, c = p % kW;
        int rr = reflect_idx(h + i - 2, kH);
        float m = 0.0f;
#pragma unroll
        for (int n = 0; n < kNBox; ++n) {
            bool in = (rr >= sy1[n]) && (rr <= sy2[n]) && (c >= sx1[n]) && (c <= sx2[n]);
            m = in ? 1.0f : m;
        }
        smask[i][c] = m;
    }
    __syncthreads();

    if (t < kW) {
        float acc = 0.0f;
#pragma unroll
        for (int i = 0; i < 5; ++i) {
#pragma unroll
            for (int j = 0; j < 5; ++j) {
                int cc = reflect_idx(t + j - 2, kW);
                acc += sk[i * 5 + j] * smask[i][cc];
            }
        }
        sfac[t] = 1.0f + kAlpha * acc;
    }
    __syncthreads();

    const int j = t % 20;
    const int c0 = t / 20;
    const float4 f4 = *reinterpret_cast<const float4*>(&sfac[j * 4]);
    const size_t rowbase = (size_t)b * (kC * kH * kW / 4) + (size_t)h * (kW / 4);
    const float4* x4 = reinterpret_cast<const float4*>(x) + rowbase;
    float4* o4 = reinterpret_cast<float4*>(out) + rowbase;
#pragma unroll
    for (int it = 0; it < kC / 16; ++it) {
        int c = c0 + it * 16;
        size_t off = (size_t)c * (kH * kW / 4) + j;
        float4 v = x4[off];
        v.x *= f4.x;
        v.y *= f4.y;
        v.z *= f4.z;
        v.w *= f4.w;
        o4[off] = v;
    }
}

extern "C" void kernel_launch(void* const* d_in, const int* in_sizes, int n_in,
                              void* d_out, int out_size, void* d_ws, size_t ws_size,
                              hipStream_t stream) {
    const float* x     = (const float*)d_in[0];
    const float* boxes = (const float*)d_in[1];
    const float* gk    = (const float*)d_in[2];
    float* out         = (float*)d_out;

    if (ws_size >= kWsNeed) {
        float* fac = (float*)d_ws;
        ae_rasterize_kernel<<<dim3(kB * 10), dim3(256), 0, stream>>>(boxes, gk, fac);
        ae_stream_kernel<<<dim3(kB * 200), dim3(256), 0, stream>>>(
            (const vfloat4*)x, (const vfloat4*)fac, (vfloat4*)out);
    } else {
        ae_fused_kernel<<<dim3(kB * kH), dim3(320), 0, stream>>>(x, boxes, gk, out);
    }
}